// Round 2
// baseline (1240.165 us; speedup 1.0000x reference)
//
#include <hip/hip_runtime.h>
#include <hip/hip_bf16.h>
#include <math.h>

typedef __hip_bfloat16 bf16;

#define B_ 8
#define C_ 256
#define HW_ 4096
#define TC_ 768     // 3*C
#define NH_ 8
#define CH_ 32      // C/NH
#define HID_ 307

__device__ __forceinline__ float ldf(const float* p) { return *p; }
__device__ __forceinline__ float ldf(const bf16* p)  { return __bfloat162float(*p); }
__device__ __forceinline__ void  stf(float* p, float v) { *p = v; }
__device__ __forceinline__ void  stf(bf16* p, float v)  { *p = __float2bfloat16(v); }

// ---------------------------------------------------------------------------
// Generic tiled GEMM: out[bt] = act(W @ X[bt] + bias) + res[bt]
// W: [M,K] row-major fp32, X: [BT, K, N], out: [BT, M, N], res: [BT,M,N] fp32 or null
// act: 0 = none, 1 = gelu(tanh approx)
// ---------------------------------------------------------------------------
template <typename TX, typename TOut>
__global__ __launch_bounds__(256) void gemm_kernel(
    const float* __restrict__ W, const TX* __restrict__ X,
    const float* __restrict__ bias, const float* __restrict__ res,
    TOut* __restrict__ out, int M, int N, int K, int act)
{
    int bt = blockIdx.z;
    X   += (size_t)bt * K * N;
    out += (size_t)bt * M * N;
    if (res) res += (size_t)bt * M * N;
    int m0 = blockIdx.y * 64, n0 = blockIdx.x * 64;

    __shared__ float Ws[16][66];   // [k][m]
    __shared__ float Xs[16][66];   // [k][n]

    int tid = threadIdx.x;
    int tx = tid & 15, ty = tid >> 4;
    float acc[4][4] = {};

    for (int k0 = 0; k0 < K; k0 += 16) {
        #pragma unroll
        for (int i = 0; i < 4; i++) {
            int l = tid + 256 * i;          // 0..1023
            int ml = l >> 4, kk = l & 15;
            float v = 0.f;
            if (m0 + ml < M && k0 + kk < K)
                v = W[(size_t)(m0 + ml) * K + k0 + kk];
            Ws[kk][ml] = v;
        }
        #pragma unroll
        for (int i = 0; i < 4; i++) {
            int l = tid + 256 * i;
            int kk = l >> 6, nl = l & 63;
            float v = 0.f;
            if (k0 + kk < K)
                v = ldf(&X[(size_t)(k0 + kk) * N + n0 + nl]);
            Xs[kk][nl] = v;
        }
        __syncthreads();
        #pragma unroll
        for (int kk = 0; kk < 16; kk++) {
            float a[4], bv[4];
            #pragma unroll
            for (int i = 0; i < 4; i++) a[i]  = Ws[kk][ty * 4 + i];
            #pragma unroll
            for (int j = 0; j < 4; j++) bv[j] = Xs[kk][tx * 4 + j];
            #pragma unroll
            for (int i = 0; i < 4; i++)
                #pragma unroll
                for (int j = 0; j < 4; j++)
                    acc[i][j] += a[i] * bv[j];
        }
        __syncthreads();
    }

    #pragma unroll
    for (int i = 0; i < 4; i++) {
        int m = m0 + ty * 4 + i;
        if (m >= M) break;
        float bvv = bias ? bias[m] : 0.f;
        #pragma unroll
        for (int j = 0; j < 4; j++) {
            int n = n0 + tx * 4 + j;
            float v = acc[i][j] + bvv;
            if (act == 1) {
                float u = v;
                float c = 0.7978845608028654f * (u + 0.044715f * u * u * u);
                v = 0.5f * u * (1.f + tanhf(c));
            }
            if (res) v += res[(size_t)m * N + n];
            stf(&out[(size_t)m * N + n], v);
        }
    }
}

// ---------------------------------------------------------------------------
// Depthwise 3x3, stride 1, pad 1.  in/out: [B, TC, 64, 64] bf16, wdw: [TC,9] fp32
// ---------------------------------------------------------------------------
__global__ __launch_bounds__(256) void dwconv_kernel(
    const bf16* __restrict__ in, const float* __restrict__ wdw,
    bf16* __restrict__ out)
{
    size_t gid = (size_t)blockIdx.x * 256 + threadIdx.x;
    int pix  = (int)(gid & 4095);
    int xcol = pix & 63, yrow = pix >> 6;
    size_t plane = gid >> 12;            // b*TC + c
    int c = (int)(plane % TC_);
    const bf16* ip = in + (plane << 12);

    float wv[9];
    #pragma unroll
    for (int t = 0; t < 9; t++) wv[t] = wdw[c * 9 + t];

    float acc = 0.f;
    #pragma unroll
    for (int dy = -1; dy <= 1; dy++) {
        int yy = yrow + dy;
        if (yy < 0 || yy > 63) continue;
        #pragma unroll
        for (int dx = -1; dx <= 1; dx++) {
            int xx = xcol + dx;
            if (xx < 0 || xx > 63) continue;
            acc += wv[(dy + 1) * 3 + (dx + 1)] * __bfloat162float(ip[yy * 64 + xx]);
        }
    }
    out[gid] = __float2bfloat16(acc);
}

// ---------------------------------------------------------------------------
// Channel attention (MDTA).  One block per (b, head).  256 threads.
// qkv: [B, 3C, HW] bf16; temp: [NH] fp32; out: [B, C, HW] fp32
// ---------------------------------------------------------------------------
__global__ __launch_bounds__(256) void attn_kernel(
    const bf16* __restrict__ qkv, const float* __restrict__ temp,
    float* __restrict__ out)
{
    int b = blockIdx.x >> 3, h = blockIdx.x & 7;
    const bf16* qp = qkv + ((size_t)b * TC_ + h * CH_) * HW_;
    const bf16* kp = qp + (size_t)C_ * HW_;
    const bf16* vp = qp + (size_t)(2 * C_) * HW_;

    __shared__ float nq[32], nk[32];
    __shared__ float qs[32][65], ks[32][65];
    __shared__ float attn[32][33];
    __shared__ float vs[32][257];

    int tid = threadIdx.x;
    int lane = tid & 63, wave = tid >> 6;

    // row L2 norms of q and k (wave w handles rows w*8 .. w*8+7)
    for (int t = 0; t < 8; t++) {
        int r = wave * 8 + t;
        const bf16* rq = qp + (size_t)r * HW_;
        const bf16* rk = kp + (size_t)r * HW_;
        float sq = 0.f, sk = 0.f;
        for (int j = lane; j < HW_; j += 64) {
            float vq = __bfloat162float(rq[j]); sq += vq * vq;
            float vk = __bfloat162float(rk[j]); sk += vk * vk;
        }
        #pragma unroll
        for (int off = 32; off; off >>= 1) {
            sq += __shfl_xor(sq, off);
            sk += __shfl_xor(sk, off);
        }
        if (lane == 0) {
            nq[r] = fmaxf(sqrtf(sq), 1e-12f);
            nk[r] = fmaxf(sqrtf(sk), 1e-12f);
        }
    }
    __syncthreads();

    // attn[i][j] = dot(q_i, k_j) over 4096, chunked through LDS
    float accA[4] = {0.f, 0.f, 0.f, 0.f};
    for (int c0 = 0; c0 < HW_; c0 += 64) {
        #pragma unroll
        for (int i = 0; i < 8; i++) {
            int l = tid + 256 * i;          // 0..2047
            int r = l >> 6, cc = l & 63;
            qs[r][cc] = __bfloat162float(qp[(size_t)r * HW_ + c0 + cc]);
            ks[r][cc] = __bfloat162float(kp[(size_t)r * HW_ + c0 + cc]);
        }
        __syncthreads();
        #pragma unroll
        for (int p = 0; p < 4; p++) {
            int e = tid + 256 * p;
            int i = e >> 5, j = e & 31;
            float s = 0.f;
            #pragma unroll
            for (int kk = 0; kk < 64; kk++) s += qs[i][kk] * ks[j][kk];
            accA[p] += s;
        }
        __syncthreads();
    }

    float tp = temp[h];
    #pragma unroll
    for (int p = 0; p < 4; p++) {
        int e = tid + 256 * p;
        int i = e >> 5, j = e & 31;
        attn[i][j] = accA[p] * tp / (nq[i] * nk[j]);
    }
    __syncthreads();

    // softmax along j (rows of attn)
    if (tid < 32) {
        float m = -1e30f;
        for (int j = 0; j < 32; j++) m = fmaxf(m, attn[tid][j]);
        float s = 0.f;
        for (int j = 0; j < 32; j++) {
            float e = expf(attn[tid][j] - m);
            attn[tid][j] = e; s += e;
        }
        float inv = 1.f / s;
        for (int j = 0; j < 32; j++) attn[tid][j] *= inv;
    }
    __syncthreads();

    // out[i][n] = sum_j attn[i][j] * v[j][n]
    float* op = out + ((size_t)b * C_ + h * CH_) * HW_;
    for (int n0 = 0; n0 < HW_; n0 += 256) {
        for (int i = 0; i < 32; i++)
            vs[i][tid] = __bfloat162float(vp[(size_t)i * HW_ + n0 + tid]);
        __syncthreads();
        for (int i = 0; i < 32; i++) {
            float s = 0.f;
            #pragma unroll
            for (int j = 0; j < 32; j++) s += attn[i][j] * vs[j][tid];
            op[(size_t)i * HW_ + n0 + tid] = s;
        }
        __syncthreads();
    }
}

// ---------------------------------------------------------------------------
extern "C" void kernel_launch(void* const* d_in, const int* in_sizes, int n_in,
                              void* d_out, int out_size, void* d_ws, size_t ws_size,
                              hipStream_t stream)
{
    const float* x      = (const float*)d_in[0];
    const float* w_qkv  = (const float*)d_in[1];
    const float* w_dw   = (const float*)d_in[2];
    const float* temp   = (const float*)d_in[3];
    const float* w_proj = (const float*)d_in[4];
    const float* w_mlp1 = (const float*)d_in[5];
    const float* b_mlp1 = (const float*)d_in[6];
    const float* w_mlp2 = (const float*)d_in[7];
    const float* b_mlp2 = (const float*)d_in[8];

    char* ws = (char*)d_ws;
    // bf16 qkv_pre [B,TC,HW] @ 0                      (50,331,648 B)
    // bf16 qkv     [B,TC,HW] @ 50,331,648             (50,331,648 B)
    // f32  attn_out [B,C,HW] @ 0        (reuse, 33,554,432 B <= qkv_pre size)
    // f32  x2       [B,C,HW] @ 33,554,432             (33,554,432 B)
    // bf16 ybuf   [B,HID,HW] @ 67,108,864             (20,119,552 B)
    bf16*  qkv_pre  = (bf16*)ws;
    bf16*  qkv      = (bf16*)(ws + (size_t)50331648);
    float* attn_out = (float*)ws;
    float* x2       = (float*)(ws + (size_t)33554432);
    bf16*  ybuf     = (bf16*)(ws + (size_t)67108864);

    // 1) qkv_pre = w_qkv @ x          (M=768, K=256, N=4096, BT=8)
    gemm_kernel<float, bf16><<<dim3(64, 12, 8), 256, 0, stream>>>(
        w_qkv, x, nullptr, nullptr, qkv_pre, TC_, HW_, C_, 0);

    // 2) qkv = dwconv3x3(qkv_pre)
    dwconv_kernel<<<(B_ * TC_ * HW_) / 256, 256, 0, stream>>>(qkv_pre, w_dw, qkv);

    // 3) attention -> attn_out
    attn_kernel<<<B_ * NH_, 256, 0, stream>>>(qkv, temp, attn_out);

    // 4) x2 = x + w_proj @ attn_out   (M=256, K=256)
    gemm_kernel<float, float><<<dim3(64, 4, 8), 256, 0, stream>>>(
        w_proj, attn_out, nullptr, x, x2, C_, HW_, C_, 0);

    // 5) y = gelu(w_mlp1 @ x2 + b1)   (M=307, K=256)
    gemm_kernel<float, bf16><<<dim3(64, 5, 8), 256, 0, stream>>>(
        w_mlp1, x2, b_mlp1, nullptr, ybuf, HID_, HW_, C_, 1);

    // 6) out = x2 + w_mlp2 @ y + b2   (M=256, K=307)
    gemm_kernel<bf16, float><<<dim3(64, 4, 8), 256, 0, stream>>>(
        w_mlp2, ybuf, b_mlp2, x2, (float*)d_out, C_, HW_, HID_, 0);
}

// Round 3
// 854.707 us; speedup vs baseline: 1.4510x; 1.4510x over previous
//
#include <hip/hip_runtime.h>
#include <hip/hip_bf16.h>
#include <math.h>

typedef __hip_bfloat16 bf16;

#define B_ 8
#define C_ 256
#define HW_ 4096
#define TC_ 768     // 3*C
#define NH_ 8
#define CH_ 32      // C/NH
#define HID_ 307

__device__ __forceinline__ float ldf(const float* p) { return *p; }
__device__ __forceinline__ float ldf(const bf16* p)  { return __bfloat162float(*p); }
__device__ __forceinline__ void  stf(float* p, float v) { *p = v; }
__device__ __forceinline__ void  stf(bf16* p, float v)  { *p = __float2bfloat16(v); }

// ---------------------------------------------------------------------------
// Generic tiled GEMM: out[bt] = act(W[bt] @ X[bt] + bias) + res[bt]
// W: [M,K] fp32 (per-bt stride wstride elems), X: [bt stride xstride elems, K,N]
// act: 0 = none, 1 = gelu(tanh approx)
// ---------------------------------------------------------------------------
template <typename TX, typename TOut>
__global__ __launch_bounds__(256) void gemm_kernel(
    const float* __restrict__ W, const TX* __restrict__ X,
    const float* __restrict__ bias, const float* __restrict__ res,
    TOut* __restrict__ out, int M, int N, int K, int act,
    size_t wstride, size_t xstride)
{
    int bt = blockIdx.z;
    W   += (size_t)bt * wstride;
    X   += (size_t)bt * xstride;
    out += (size_t)bt * M * N;
    if (res) res += (size_t)bt * M * N;
    int m0 = blockIdx.y * 64, n0 = blockIdx.x * 64;

    __shared__ float Ws[16][66];   // [k][m]
    __shared__ float Xs[16][66];   // [k][n]

    int tid = threadIdx.x;
    int tx = tid & 15, ty = tid >> 4;
    float acc[4][4] = {};

    for (int k0 = 0; k0 < K; k0 += 16) {
        #pragma unroll
        for (int i = 0; i < 4; i++) {
            int l = tid + 256 * i;          // 0..1023
            int ml = l >> 4, kk = l & 15;
            float v = 0.f;
            if (m0 + ml < M && k0 + kk < K)
                v = W[(size_t)(m0 + ml) * K + k0 + kk];
            Ws[kk][ml] = v;
        }
        #pragma unroll
        for (int i = 0; i < 4; i++) {
            int l = tid + 256 * i;
            int kk = l >> 6, nl = l & 63;
            float v = 0.f;
            if (k0 + kk < K)
                v = ldf(&X[(size_t)(k0 + kk) * N + n0 + nl]);
            Xs[kk][nl] = v;
        }
        __syncthreads();
        #pragma unroll
        for (int kk = 0; kk < 16; kk++) {
            float a[4], bv[4];
            #pragma unroll
            for (int i = 0; i < 4; i++) a[i]  = Ws[kk][ty * 4 + i];
            #pragma unroll
            for (int j = 0; j < 4; j++) bv[j] = Xs[kk][tx * 4 + j];
            #pragma unroll
            for (int i = 0; i < 4; i++)
                #pragma unroll
                for (int j = 0; j < 4; j++)
                    acc[i][j] += a[i] * bv[j];
        }
        __syncthreads();
    }

    #pragma unroll
    for (int i = 0; i < 4; i++) {
        int m = m0 + ty * 4 + i;
        if (m >= M) break;
        float bvv = bias ? bias[m] : 0.f;
        #pragma unroll
        for (int j = 0; j < 4; j++) {
            int n = n0 + tx * 4 + j;
            float v = acc[i][j] + bvv;
            if (act == 1) {
                float u = v;
                float c = 0.7978845608028654f * (u + 0.044715f * u * u * u);
                v = 0.5f * u * (1.f + tanhf(c));
            }
            if (res) v += res[(size_t)m * N + n];
            stf(&out[(size_t)m * N + n], v);
        }
    }
}

// ---------------------------------------------------------------------------
// Depthwise 3x3, stride 1, pad 1.  in/out: [B, TC, 64, 64] bf16, wdw: [TC,9] fp32
// ---------------------------------------------------------------------------
__global__ __launch_bounds__(256) void dwconv_kernel(
    const bf16* __restrict__ in, const float* __restrict__ wdw,
    bf16* __restrict__ out)
{
    size_t gid = (size_t)blockIdx.x * 256 + threadIdx.x;
    int pix  = (int)(gid & 4095);
    int xcol = pix & 63, yrow = pix >> 6;
    size_t plane = gid >> 12;            // b*TC + c
    int c = (int)(plane % TC_);
    const bf16* ip = in + (plane << 12);

    float wv[9];
    #pragma unroll
    for (int t = 0; t < 9; t++) wv[t] = wdw[c * 9 + t];

    float acc = 0.f;
    #pragma unroll
    for (int dy = -1; dy <= 1; dy++) {
        int yy = yrow + dy;
        if (yy < 0 || yy > 63) continue;
        #pragma unroll
        for (int dx = -1; dx <= 1; dx++) {
            int xx = xcol + dx;
            if (xx < 0 || xx > 63) continue;
            acc += wv[(dy + 1) * 3 + (dx + 1)] * __bfloat162float(ip[yy * 64 + xx]);
        }
    }
    out[gid] = __float2bfloat16(acc);
}

// ---------------------------------------------------------------------------
// Zero-init fp32 scratch (S, n2q, n2k are atomically accumulated).
// ---------------------------------------------------------------------------
__global__ void zero_kernel(float* __restrict__ p, int n)
{
    int i = blockIdx.x * 256 + threadIdx.x;
    if (i < n) p[i] = 0.f;
}

// ---------------------------------------------------------------------------
// Stage A: partial QK^T + partial squared norms per (b,h), chunked over pixels.
// grid: (chunks=8, bh=64), 256 threads.  chunk = 512 pixels, 8 subtiles of 64.
// ---------------------------------------------------------------------------
__global__ __launch_bounds__(256) void qk_partial_kernel(
    const bf16* __restrict__ qkv, float* __restrict__ S,
    float* __restrict__ n2q, float* __restrict__ n2k)
{
    int bh = blockIdx.y;
    int b = bh >> 3, h = bh & 7;
    int base = blockIdx.x * 512;
    const bf16* qp = qkv + ((size_t)b * TC_ + h * CH_) * HW_;
    const bf16* kp = qp + (size_t)C_ * HW_;

    __shared__ float qs[32][65], ks[32][65];

    int tid = threadIdx.x;
    int nr = tid >> 3, seg = (tid & 7) * 8;     // norm row / 8-px segment
    float accA[4] = {0.f, 0.f, 0.f, 0.f};
    float sq = 0.f, sk = 0.f;

    for (int t0 = 0; t0 < 512; t0 += 64) {
        #pragma unroll
        for (int i = 0; i < 8; i++) {
            int l = tid + 256 * i;              // 0..2047
            int r = l >> 6, cc = l & 63;
            qs[r][cc] = __bfloat162float(qp[(size_t)r * HW_ + base + t0 + cc]);
            ks[r][cc] = __bfloat162float(kp[(size_t)r * HW_ + base + t0 + cc]);
        }
        __syncthreads();
        #pragma unroll
        for (int p = 0; p < 4; p++) {
            int e = tid + 256 * p;
            int i = e >> 5, j = e & 31;
            float s = 0.f;
            #pragma unroll
            for (int kk = 0; kk < 64; kk++) s += qs[i][kk] * ks[j][kk];
            accA[p] += s;
        }
        #pragma unroll
        for (int s = 0; s < 8; s++) {
            float vq = qs[nr][seg + s]; sq += vq * vq;
            float vk = ks[nr][seg + s]; sk += vk * vk;
        }
        __syncthreads();
    }

    // reduce norms within 8-lane groups
    #pragma unroll
    for (int off = 1; off < 8; off <<= 1) {
        sq += __shfl_xor(sq, off);
        sk += __shfl_xor(sk, off);
    }
    if ((tid & 7) == 0) {
        atomicAdd(&n2q[bh * 32 + nr], sq);
        atomicAdd(&n2k[bh * 32 + nr], sk);
    }
    #pragma unroll
    for (int p = 0; p < 4; p++) {
        int e = tid + 256 * p;                  // e == i*32+j
        atomicAdd(&S[(size_t)bh * 1024 + e], accA[p]);
    }
}

// ---------------------------------------------------------------------------
// Stage B: normalize + softmax.  grid: 64 blocks (bh), 64 threads.
// ---------------------------------------------------------------------------
__global__ __launch_bounds__(64) void softmax_kernel(
    const float* __restrict__ S, const float* __restrict__ n2q,
    const float* __restrict__ n2k, const float* __restrict__ temp,
    float* __restrict__ attnb)
{
    int bh = blockIdx.x, h = bh & 7;
    __shared__ float nkl[32];
    int tid = threadIdx.x;
    if (tid < 32) nkl[tid] = fmaxf(sqrtf(n2k[bh * 32 + tid]), 1e-12f);
    __syncthreads();
    if (tid < 32) {
        float nq = fmaxf(sqrtf(n2q[bh * 32 + tid]), 1e-12f);
        float tp = temp[h];
        float row[32];
        float m = -1e30f;
        #pragma unroll
        for (int j = 0; j < 32; j++) {
            row[j] = S[(size_t)bh * 1024 + tid * 32 + j] * tp / (nq * nkl[j]);
            m = fmaxf(m, row[j]);
        }
        float s = 0.f;
        #pragma unroll
        for (int j = 0; j < 32; j++) { row[j] = expf(row[j] - m); s += row[j]; }
        float inv = 1.f / s;
        #pragma unroll
        for (int j = 0; j < 32; j++)
            attnb[(size_t)bh * 1024 + tid * 32 + j] = row[j] * inv;
    }
}

// ---------------------------------------------------------------------------
// Stage C: Wcomb[b][m][h*32+j] = sum_i w_proj[m][h*32+i] * attn[b][h][i][j]
// grid: 64 blocks (bh), 256 threads (m).
// ---------------------------------------------------------------------------
__global__ __launch_bounds__(256) void wcomb_kernel(
    const float* __restrict__ w_proj, const float* __restrict__ attnb,
    float* __restrict__ wcomb)
{
    int bh = blockIdx.x;
    int b = bh >> 3, h = bh & 7;
    __shared__ float at[32][33];
    int tid = threadIdx.x;
    #pragma unroll
    for (int p = 0; p < 4; p++) {
        int e = tid + 256 * p;
        at[e >> 5][e & 31] = attnb[(size_t)bh * 1024 + e];
    }
    __syncthreads();
    int m = tid;
    float wrow[32];
    #pragma unroll
    for (int i = 0; i < 32; i++) wrow[i] = w_proj[(size_t)m * C_ + h * 32 + i];
    #pragma unroll
    for (int j = 0; j < 32; j++) {
        float s = 0.f;
        #pragma unroll
        for (int i = 0; i < 32; i++) s += wrow[i] * at[i][j];
        wcomb[((size_t)b * C_ + m) * C_ + h * 32 + j] = s;
    }
}

// ---------------------------------------------------------------------------
extern "C" void kernel_launch(void* const* d_in, const int* in_sizes, int n_in,
                              void* d_out, int out_size, void* d_ws, size_t ws_size,
                              hipStream_t stream)
{
    const float* x      = (const float*)d_in[0];
    const float* w_qkv  = (const float*)d_in[1];
    const float* w_dw   = (const float*)d_in[2];
    const float* temp   = (const float*)d_in[3];
    const float* w_proj = (const float*)d_in[4];
    const float* w_mlp1 = (const float*)d_in[5];
    const float* b_mlp1 = (const float*)d_in[6];
    const float* w_mlp2 = (const float*)d_in[7];
    const float* b_mlp2 = (const float*)d_in[8];

    char* ws = (char*)d_ws;
    // region [0, 50.33MB): qkv_pre bf16, then reused:
    //   x2 fp32 @0 (33.55MB); S @33,554,432; n2q/n2k; attnb; Wcomb
    // region [50.33MB, 100.66MB): qkv bf16, then ybuf bf16 reuses its start
    bf16*  qkv_pre = (bf16*)ws;
    bf16*  qkv     = (bf16*)(ws + (size_t)50331648);
    float* x2      = (float*)ws;
    float* S_f     = (float*)(ws + (size_t)33554432);   // 65536 floats
    float* n2q     = S_f + 65536;                       // 2048
    float* n2k     = n2q + 2048;                        // 2048
    float* attnb   = n2k + 2048;                        // 65536
    float* wcomb   = attnb + 65536;                     // 524288 (2MB)
    bf16*  ybuf    = (bf16*)(ws + (size_t)50331648);    // reuses qkv (dead after GEMM4)

    // 1) qkv_pre = w_qkv @ x          (M=768, K=256, N=4096, BT=8)
    gemm_kernel<float, bf16><<<dim3(64, 12, 8), 256, 0, stream>>>(
        w_qkv, x, nullptr, nullptr, qkv_pre, TC_, HW_, C_, 0,
        0, (size_t)C_ * HW_);

    // 2) qkv = dwconv3x3(qkv_pre)
    dwconv_kernel<<<(B_ * TC_ * HW_) / 256, 256, 0, stream>>>(qkv_pre, w_dw, qkv);

    // 3) zero atomically-accumulated scratch (S, n2q, n2k contiguous: 69632 f)
    zero_kernel<<<(69632 + 255) / 256, 256, 0, stream>>>(S_f, 69632);

    // 4) partial QK^T + norms
    qk_partial_kernel<<<dim3(8, 64), 256, 0, stream>>>(qkv, S_f, n2q, n2k);

    // 5) softmax -> attnb
    softmax_kernel<<<64, 64, 0, stream>>>(S_f, n2q, n2k, temp, attnb);

    // 6) Wcomb[b] = w_proj @ blockdiag(attn[b])
    wcomb_kernel<<<64, 256, 0, stream>>>(w_proj, attnb, wcomb);

    // 7) x2 = x + Wcomb[b] @ v        (M=256, K=256, v inside qkv)
    gemm_kernel<bf16, float><<<dim3(64, 4, 8), 256, 0, stream>>>(
        wcomb, qkv + (size_t)2 * C_ * HW_, nullptr, x, x2, C_, HW_, C_, 0,
        (size_t)C_ * C_, (size_t)TC_ * HW_);

    // 8) y = gelu(w_mlp1 @ x2 + b1)   (M=307, K=256)
    gemm_kernel<float, bf16><<<dim3(64, 5, 8), 256, 0, stream>>>(
        w_mlp1, x2, b_mlp1, nullptr, ybuf, HID_, HW_, C_, 1,
        0, (size_t)C_ * HW_);

    // 9) out = x2 + w_mlp2 @ y + b2   (M=256, K=307)
    gemm_kernel<bf16, float><<<dim3(64, 4, 8), 256, 0, stream>>>(
        w_mlp2, ybuf, b_mlp2, x2, (float*)d_out, C_, HW_, HID_, 0,
        0, (size_t)HID_ * HW_);
}

// Round 4
// 443.829 us; speedup vs baseline: 2.7942x; 1.9258x over previous
//
#include <hip/hip_runtime.h>
#include <hip/hip_bf16.h>
#include <math.h>

typedef __hip_bfloat16 bf16;
using s16x8 = __attribute__((ext_vector_type(8))) short;
using f32x4 = __attribute__((ext_vector_type(4))) float;

#define B_ 8
#define C_ 256
#define HW_ 4096
#define TC_ 768     // 3*C
#define NH_ 8
#define CH_ 32      // C/NH
#define HID_ 307
#define HIDP_ 320   // K padded for gemm9
#define HIDM_ 384   // M padded rows for w_mlp1 bf16 buffer

__device__ __forceinline__ float ldf(const float* p) { return *p; }
__device__ __forceinline__ float ldf(const bf16* p)  { return __bfloat162float(*p); }
__device__ __forceinline__ void  stf(float* p, float v) { *p = v; }
__device__ __forceinline__ void  stf(bf16* p, float v)  { *p = __float2bfloat16(v); }

__device__ __forceinline__ float gelu_tanh(float u) {
    float c = 0.7978845608028654f * (u + 0.044715f * u * u * u);
    return 0.5f * u * (1.f + tanhf(c));
}

// async global->LDS 16B: dest = lbase + lane*16 (wave-uniform lbase)
__device__ __forceinline__ void stage16(const void* g, uint32_t* lbase, int lane) {
#if __has_builtin(__builtin_amdgcn_global_load_lds)
    __builtin_amdgcn_global_load_lds(
        (const __attribute__((address_space(1))) uint32_t*)g,
        (__attribute__((address_space(3))) uint32_t*)lbase, 16, 0, 0);
#else
    ((uint4*)lbase)[lane] = *(const uint4*)g;
#endif
}

// ---------------------------------------------------------------------------
// MFMA GEMM: out[bt] = act(A[bt] @ Xt[bt]^T + bias) + res[bt]
// A: [Mpad][Kp] bf16 row-major (K-contig), Xt: [N][Kp] bf16 (K-contig)
// out: [M][N].  Kp multiple of 64.  Tile 128x128, BK=64, 4 waves.
// LDS layout: A-tile units 0..1023 (16B units), B-tile units 1024..2047,
// unit(row,u) swizzled: u_sw = u ^ (row&7).
// ---------------------------------------------------------------------------
template <typename TOut>
__global__ __launch_bounds__(256) void mfma_gemm(
    const bf16* __restrict__ A, const bf16* __restrict__ Xt,
    const float* __restrict__ bias, const float* __restrict__ res,
    TOut* __restrict__ out, int M, int N, int Kp, int act,
    size_t astride, size_t xstride, size_t ostride)
{
    int bt = blockIdx.z;
    A  += (size_t)bt * astride;
    Xt += (size_t)bt * xstride;
    out += (size_t)bt * ostride;
    if (res) res += (size_t)bt * ostride;
    int m0 = blockIdx.y * 128, n0 = blockIdx.x * 128;

    __shared__ uint32_t lds[8192];   // 32 KB

    int tid = threadIdx.x;
    int w = tid >> 6, lane = tid & 63;
    int wr = w >> 1, wc = w & 1;
    int r15 = lane & 15, g = lane >> 4;

    f32x4 zero4 = {0.f, 0.f, 0.f, 0.f};
    f32x4 acc[4][4];
    #pragma unroll
    for (int i = 0; i < 4; i++)
        #pragma unroll
        for (int j = 0; j < 4; j++) acc[i][j] = zero4;

    int nkt = Kp >> 6;
    for (int kt = 0; kt < nkt; kt++) {
        // ---- stage A and B tiles (linear LDS dest, inverse-swizzled source)
        #pragma unroll
        for (int i = 0; i < 4; i++) {
            int row = (w * 4 + i) * 8 + (lane >> 3);   // 0..127
            int us  = (lane & 7) ^ (row & 7);          // source 16B-unit in row
            const bf16* sa = A  + (size_t)(m0 + row) * Kp + kt * 64 + us * 8;
            const bf16* sb = Xt + (size_t)(n0 + row) * Kp + kt * 64 + us * 8;
            stage16(sa, &lds[(w * 4 + i) * 256], lane);
            stage16(sb, &lds[4096 + (w * 4 + i) * 256], lane);
        }
        __syncthreads();

        // ---- fragment reads (swizzled)
        s16x8 af[4][2], bfr[4][2];
        #pragma unroll
        for (int mm = 0; mm < 4; mm++) {
            int r = wr * 64 + mm * 16 + r15;
            #pragma unroll
            for (int ks = 0; ks < 2; ks++) {
                int u = (ks * 4 + g) ^ (r & 7);
                af[mm][ks] = *(const s16x8*)&lds[(unsigned)(r * 8 + u) * 4];
            }
        }
        #pragma unroll
        for (int nn = 0; nn < 4; nn++) {
            int r = wc * 64 + nn * 16 + r15;
            #pragma unroll
            for (int ks = 0; ks < 2; ks++) {
                int u = (ks * 4 + g) ^ (r & 7);
                bfr[nn][ks] = *(const s16x8*)&lds[4096 + (unsigned)(r * 8 + u) * 4];
            }
        }

        #pragma unroll
        for (int ks = 0; ks < 2; ks++)
            #pragma unroll
            for (int mm = 0; mm < 4; mm++)
                #pragma unroll
                for (int nn = 0; nn < 4; nn++)
                    acc[mm][nn] = __builtin_amdgcn_mfma_f32_16x16x32_bf16(
                        af[mm][ks], bfr[nn][ks], acc[mm][nn], 0, 0, 0);
        __syncthreads();
    }

    // ---- epilogue: m = m0 + wr*64 + mm*16 + (lane>>4)*4 + rr, n = ... + (lane&15)
    #pragma unroll
    for (int mm = 0; mm < 4; mm++) {
        int mbase = m0 + wr * 64 + mm * 16 + g * 4;
        #pragma unroll
        for (int rr = 0; rr < 4; rr++) {
            int m = mbase + rr;
            if (m >= M) continue;
            float bv = bias ? bias[m] : 0.f;
            #pragma unroll
            for (int nn = 0; nn < 4; nn++) {
                int n = n0 + wc * 64 + nn * 16 + r15;
                float v = acc[mm][nn][rr] + bv;
                if (act == 1) v = gelu_tanh(v);
                if (res) v += res[(size_t)m * N + n];
                stf(&out[(size_t)m * N + n], v);
            }
        }
    }
}

// ---------------------------------------------------------------------------
// Transpose-convert: out[n][r] = bf16(in[r][n]) for r<R else 0.  out: [Ncols][Rpad]
// ---------------------------------------------------------------------------
template <typename TIn>
__global__ __launch_bounds__(256) void transpose_kernel(
    const TIn* __restrict__ in, bf16* __restrict__ out,
    int R, int Ncols, int Rpad, size_t in_z, size_t out_z)
{
    in  += (size_t)blockIdx.z * in_z;
    out += (size_t)blockIdx.z * out_z;
    __shared__ float t[32][33];
    int r0 = blockIdx.y * 32, n0 = blockIdx.x * 32;
    int tx = threadIdx.x & 31, ty = threadIdx.x >> 5;
    #pragma unroll
    for (int s = 0; s < 4; s++) {
        int r = r0 + ty + 8 * s;
        t[ty + 8 * s][tx] = (r < R) ? ldf(&in[(size_t)r * Ncols + n0 + tx]) : 0.f;
    }
    __syncthreads();
    #pragma unroll
    for (int s = 0; s < 4; s++) {
        int n = n0 + ty + 8 * s;
        out[(size_t)n * Rpad + r0 + tx] = __float2bfloat16(t[tx][ty + 8 * s]);
    }
}

// ---------------------------------------------------------------------------
// fp32 [R][Cin] -> bf16 [Rpad][Cout], zero-padded
// ---------------------------------------------------------------------------
__global__ __launch_bounds__(256) void convert_pad_kernel(
    const float* __restrict__ in, bf16* __restrict__ out,
    int R, int Cin, int Cout)
{
    int c = blockIdx.x * 256 + threadIdx.x;
    int r = blockIdx.y;
    if (c >= Cout) return;
    float v = (r < R && c < Cin) ? in[(size_t)r * Cin + c] : 0.f;
    out[(size_t)r * Cout + c] = __float2bfloat16(v);
}

// ---------------------------------------------------------------------------
// Depthwise 3x3, stride 1, pad 1.  in/out: [B, TC, 64, 64] bf16, wdw: [TC,9] fp32
// ---------------------------------------------------------------------------
__global__ __launch_bounds__(256) void dwconv_kernel(
    const bf16* __restrict__ in, const float* __restrict__ wdw,
    bf16* __restrict__ out)
{
    size_t gid = (size_t)blockIdx.x * 256 + threadIdx.x;
    int pix  = (int)(gid & 4095);
    int xcol = pix & 63, yrow = pix >> 6;
    size_t plane = gid >> 12;            // b*TC + c
    int c = (int)(plane % TC_);
    const bf16* ip = in + (plane << 12);

    float wv[9];
    #pragma unroll
    for (int t = 0; t < 9; t++) wv[t] = wdw[c * 9 + t];

    float acc = 0.f;
    #pragma unroll
    for (int dy = -1; dy <= 1; dy++) {
        int yy = yrow + dy;
        if (yy < 0 || yy > 63) continue;
        #pragma unroll
        for (int dx = -1; dx <= 1; dx++) {
            int xx = xcol + dx;
            if (xx < 0 || xx > 63) continue;
            acc += wv[(dy + 1) * 3 + (dx + 1)] * __bfloat162float(ip[yy * 64 + xx]);
        }
    }
    out[gid] = __float2bfloat16(acc);
}

__global__ void zero_kernel(float* __restrict__ p, int n)
{
    int i = blockIdx.x * 256 + threadIdx.x;
    if (i < n) p[i] = 0.f;
}

// ---------------------------------------------------------------------------
// Stage A: partial QK^T + partial squared norms per (b,h), chunked over pixels.
// grid: (chunks=8, bh=64), 256 threads.
// ---------------------------------------------------------------------------
__global__ __launch_bounds__(256) void qk_partial_kernel(
    const bf16* __restrict__ qkv, float* __restrict__ S,
    float* __restrict__ n2q, float* __restrict__ n2k)
{
    int bh = blockIdx.y;
    int b = bh >> 3, h = bh & 7;
    int base = blockIdx.x * 512;
    const bf16* qp = qkv + ((size_t)b * TC_ + h * CH_) * HW_;
    const bf16* kp = qp + (size_t)C_ * HW_;

    __shared__ float qs[32][65], ks[32][65];

    int tid = threadIdx.x;
    int nr = tid >> 3, seg = (tid & 7) * 8;
    float accA[4] = {0.f, 0.f, 0.f, 0.f};
    float sq = 0.f, sk = 0.f;

    for (int t0 = 0; t0 < 512; t0 += 64) {
        #pragma unroll
        for (int i = 0; i < 8; i++) {
            int l = tid + 256 * i;
            int r = l >> 6, cc = l & 63;
            qs[r][cc] = __bfloat162float(qp[(size_t)r * HW_ + base + t0 + cc]);
            ks[r][cc] = __bfloat162float(kp[(size_t)r * HW_ + base + t0 + cc]);
        }
        __syncthreads();
        #pragma unroll
        for (int p = 0; p < 4; p++) {
            int e = tid + 256 * p;
            int i = e >> 5, j = e & 31;
            float s = 0.f;
            #pragma unroll
            for (int kk = 0; kk < 64; kk++) s += qs[i][kk] * ks[j][kk];
            accA[p] += s;
        }
        #pragma unroll
        for (int s = 0; s < 8; s++) {
            float vq = qs[nr][seg + s]; sq += vq * vq;
            float vk = ks[nr][seg + s]; sk += vk * vk;
        }
        __syncthreads();
    }

    #pragma unroll
    for (int off = 1; off < 8; off <<= 1) {
        sq += __shfl_xor(sq, off);
        sk += __shfl_xor(sk, off);
    }
    if ((tid & 7) == 0) {
        atomicAdd(&n2q[bh * 32 + nr], sq);
        atomicAdd(&n2k[bh * 32 + nr], sk);
    }
    #pragma unroll
    for (int p = 0; p < 4; p++) {
        int e = tid + 256 * p;
        atomicAdd(&S[(size_t)bh * 1024 + e], accA[p]);
    }
}

// ---------------------------------------------------------------------------
// Stage B: normalize + softmax.  grid: 64 blocks (bh), 64 threads.
// ---------------------------------------------------------------------------
__global__ __launch_bounds__(64) void softmax_kernel(
    const float* __restrict__ S, const float* __restrict__ n2q,
    const float* __restrict__ n2k, const float* __restrict__ temp,
    float* __restrict__ attnb)
{
    int bh = blockIdx.x, h = bh & 7;
    __shared__ float nkl[32];
    int tid = threadIdx.x;
    if (tid < 32) nkl[tid] = fmaxf(sqrtf(n2k[bh * 32 + tid]), 1e-12f);
    __syncthreads();
    if (tid < 32) {
        float nq = fmaxf(sqrtf(n2q[bh * 32 + tid]), 1e-12f);
        float tp = temp[h];
        float row[32];
        float m = -1e30f;
        #pragma unroll
        for (int j = 0; j < 32; j++) {
            row[j] = S[(size_t)bh * 1024 + tid * 32 + j] * tp / (nq * nkl[j]);
            m = fmaxf(m, row[j]);
        }
        float s = 0.f;
        #pragma unroll
        for (int j = 0; j < 32; j++) { row[j] = expf(row[j] - m); s += row[j]; }
        float inv = 1.f / s;
        #pragma unroll
        for (int j = 0; j < 32; j++)
            attnb[(size_t)bh * 1024 + tid * 32 + j] = row[j] * inv;
    }
}

// ---------------------------------------------------------------------------
// Stage C: Wcomb[b][m][h*32+j] = sum_i w_proj[m][h*32+i] * attn[b][h][i][j]
// out bf16.  grid: 64 blocks (bh), 256 threads (m).
// ---------------------------------------------------------------------------
__global__ __launch_bounds__(256) void wcomb_kernel(
    const float* __restrict__ w_proj, const float* __restrict__ attnb,
    bf16* __restrict__ wcomb)
{
    int bh = blockIdx.x;
    int b = bh >> 3, h = bh & 7;
    __shared__ float at[32][33];
    int tid = threadIdx.x;
    #pragma unroll
    for (int p = 0; p < 4; p++) {
        int e = tid + 256 * p;
        at[e >> 5][e & 31] = attnb[(size_t)bh * 1024 + e];
    }
    __syncthreads();
    int m = tid;
    float wrow[32];
    #pragma unroll
    for (int i = 0; i < 32; i++) wrow[i] = w_proj[(size_t)m * C_ + h * 32 + i];
    #pragma unroll
    for (int j = 0; j < 32; j++) {
        float s = 0.f;
        #pragma unroll
        for (int i = 0; i < 32; i++) s += wrow[i] * at[i][j];
        wcomb[((size_t)b * C_ + m) * C_ + h * 32 + j] = __float2bfloat16(s);
    }
}

// ---------------------------------------------------------------------------
extern "C" void kernel_launch(void* const* d_in, const int* in_sizes, int n_in,
                              void* d_out, int out_size, void* d_ws, size_t ws_size,
                              hipStream_t stream)
{
    const float* x      = (const float*)d_in[0];
    const float* w_qkv  = (const float*)d_in[1];
    const float* w_dw   = (const float*)d_in[2];
    const float* temp   = (const float*)d_in[3];
    const float* w_proj = (const float*)d_in[4];
    const float* w_mlp1 = (const float*)d_in[5];
    const float* b_mlp1 = (const float*)d_in[6];
    const float* w_mlp2 = (const float*)d_in[7];
    const float* b_mlp2 = (const float*)d_in[8];

    char* ws = (char*)d_ws;
    // Lifetime plan (bytes):
    //  qkv_pre bf16 @0              (50,331,648)  dead after dwconv
    //  xt      bf16 @50,331,648     (16,777,216)  dead after GEMM1   } inside
    //  wqkv_bf bf16 @67,108,864     (   393,216)  dead after GEMM1   } future qkv
    //  qkv     bf16 @50,331,648     (50,331,648)  written by dwconv
    //  --- after dwconv, region [0,50.33M) reused:
    //  x2      f32  @0              (33,554,432)
    //  S_f     f32  @33,554,432     (   262,144)
    //  n2q/n2k f32  following       (     16,384)
    //  attnb   f32  following       (   262,144)
    //  wcomb   bf16 @34,095,104     ( 1,048,576)
    //  wm1_bf  bf16 @35,143,680     (   196,608)
    //  wm2_bf  bf16 @35,340,288     (   163,840)
    //  vt      bf16 @35,504,128     (16,777,216)  (tail overlaps qkv b0 q-rows;
    //                                              written after qk_partial -> safe)
    //  ybuf    bf16 @52,281,344     (20,119,552)
    //  x2t     bf16 @72,400,896     (16,777,216)  dead after GEMM8
    //  yt      bf16 @72,400,896     (20,971,520)  reuses x2t slot
    bf16*  qkv_pre = (bf16*)ws;
    bf16*  xt      = (bf16*)(ws + (size_t)50331648);
    bf16*  wqkv_bf = (bf16*)(ws + (size_t)67108864);
    bf16*  qkv     = (bf16*)(ws + (size_t)50331648);
    float* x2      = (float*)ws;
    float* S_f     = (float*)(ws + (size_t)33554432);
    float* n2q     = S_f + 65536;
    float* n2k     = n2q + 2048;
    float* attnb   = n2k + 2048;
    bf16*  wcomb   = (bf16*)(ws + (size_t)34095104);
    bf16*  wm1_bf  = (bf16*)(ws + (size_t)35143680);
    bf16*  wm2_bf  = (bf16*)(ws + (size_t)35340288);
    bf16*  vt      = (bf16*)(ws + (size_t)35504128);
    bf16*  ybuf    = (bf16*)(ws + (size_t)52281344);
    bf16*  x2t     = (bf16*)(ws + (size_t)72400896);
    bf16*  yt      = (bf16*)(ws + (size_t)72400896);

    // 1) weights/inputs to bf16
    convert_pad_kernel<<<dim3(1, TC_), 256, 0, stream>>>(w_qkv, wqkv_bf, TC_, C_, C_);
    transpose_kernel<float><<<dim3(128, 8, B_), 256, 0, stream>>>(
        x, xt, C_, HW_, C_, (size_t)C_ * HW_, (size_t)HW_ * C_);

    // 2) qkv_pre = w_qkv @ x   (M=768, N=4096, K=256)
    mfma_gemm<bf16><<<dim3(32, 6, B_), 256, 0, stream>>>(
        wqkv_bf, xt, nullptr, nullptr, qkv_pre, TC_, HW_, C_, 0,
        0, (size_t)HW_ * C_, (size_t)TC_ * HW_);

    // 3) qkv = dwconv3x3(qkv_pre)
    dwconv_kernel<<<(B_ * TC_ * HW_) / 256, 256, 0, stream>>>(qkv_pre, w_dw, qkv);

    // 4) attention statistics
    zero_kernel<<<(69632 + 255) / 256, 256, 0, stream>>>(S_f, 69632);
    qk_partial_kernel<<<dim3(8, 64), 256, 0, stream>>>(qkv, S_f, n2q, n2k);
    softmax_kernel<<<64, 64, 0, stream>>>(S_f, n2q, n2k, temp, attnb);
    wcomb_kernel<<<64, 256, 0, stream>>>(w_proj, attnb, wcomb);

    // 5) remaining weight converts + v transpose
    convert_pad_kernel<<<dim3(1, HIDM_), 256, 0, stream>>>(w_mlp1, wm1_bf, HID_, C_, C_);
    convert_pad_kernel<<<dim3(2, C_), 256, 0, stream>>>(w_mlp2, wm2_bf, C_, HID_, HIDP_);
    transpose_kernel<bf16><<<dim3(128, 8, B_), 256, 0, stream>>>(
        qkv + (size_t)2 * C_ * HW_, vt, C_, HW_, C_,
        (size_t)TC_ * HW_, (size_t)HW_ * C_);

    // 6) x2 = x + Wcomb[b] @ v   (M=256, N=4096, K=256)
    mfma_gemm<float><<<dim3(32, 2, B_), 256, 0, stream>>>(
        wcomb, vt, nullptr, x, x2, C_, HW_, C_, 0,
        (size_t)C_ * C_, (size_t)HW_ * C_, (size_t)C_ * HW_);

    // 7) x2t
    transpose_kernel<float><<<dim3(128, 8, B_), 256, 0, stream>>>(
        x2, x2t, C_, HW_, C_, (size_t)C_ * HW_, (size_t)HW_ * C_);

    // 8) y = gelu(w_mlp1 @ x2 + b1)   (M=307, N=4096, K=256)
    mfma_gemm<bf16><<<dim3(32, 3, B_), 256, 0, stream>>>(
        wm1_bf, x2t, b_mlp1, nullptr, ybuf, HID_, HW_, C_, 1,
        0, (size_t)HW_ * C_, (size_t)HID_ * HW_);

    // 9) yt (pad K 307->320)
    transpose_kernel<bf16><<<dim3(128, 10, B_), 256, 0, stream>>>(
        ybuf, yt, HID_, HW_, HIDP_, (size_t)HID_ * HW_, (size_t)HW_ * HIDP_);

    // 10) out = x2 + w_mlp2 @ y + b2   (M=256, N=4096, K=320 padded)
    mfma_gemm<float><<<dim3(32, 2, B_), 256, 0, stream>>>(
        wm2_bf, yt, b_mlp2, x2, (float*)d_out, C_, HW_, HIDP_, 0,
        0, (size_t)HW_ * HIDP_, (size_t)C_ * HW_);
}

// Round 5
// 377.715 us; speedup vs baseline: 3.2833x; 1.1750x over previous
//
#include <hip/hip_runtime.h>
#include <hip/hip_bf16.h>
#include <math.h>

typedef __hip_bfloat16 bf16;
using s16x8 = __attribute__((ext_vector_type(8))) short;
using f32x4 = __attribute__((ext_vector_type(4))) float;

#define B_ 8
#define C_ 256
#define HW_ 4096
#define TC_ 768     // 3*C
#define NH_ 8
#define CH_ 32      // C/NH
#define HID_ 307
#define HIDP_ 320   // K padded for gemm10 / N padded for gemm8T
#define HIDM_ 384   // padded rows for w_mlp1 bf16 buffer

__device__ __forceinline__ float ldf(const float* p) { return *p; }
__device__ __forceinline__ float ldf(const bf16* p)  { return __bfloat162float(*p); }
__device__ __forceinline__ void  stf(float* p, float v) { *p = v; }
__device__ __forceinline__ void  stf(bf16* p, float v)  { *p = __float2bfloat16(v); }

__device__ __forceinline__ float bfu2f(unsigned short u) {
    union { unsigned int i; float f; } c; c.i = ((unsigned int)u) << 16; return c.f;
}

__device__ __forceinline__ float gelu_tanh(float u) {
    float c = 0.7978845608028654f * (u + 0.044715f * u * u * u);
    return 0.5f * u * (1.f + tanhf(c));
}

// async global->LDS 16B: dest = lbase + lane*16 (wave-uniform lbase)
__device__ __forceinline__ void stage16(const void* g, uint32_t* lbase, int lane) {
#if __has_builtin(__builtin_amdgcn_global_load_lds)
    __builtin_amdgcn_global_load_lds(
        (const __attribute__((address_space(1))) uint32_t*)g,
        (__attribute__((address_space(3))) uint32_t*)lbase, 16, 0, 0);
#else
    ((uint4*)lbase)[lane] = *(const uint4*)g;
#endif
}

// ---------------------------------------------------------------------------
// MFMA GEMM: out[bt] = act(A[bt] @ Xt[bt]^T + bias) + res[bt]
// A: [M..][Kp] bf16 (K-contig), Xt: [N..][Kp] bf16 (K-contig)
// out: [M][Nld]; writes guarded to n < Nw (and m < M).
// bias_on_n: bias indexed by n (guarded to n < bias_len) instead of m.
// Tile 128x128, BK=64, 4 waves, swizzled LDS (rule 21: inv-swz source + swz read).
// ---------------------------------------------------------------------------
template <typename TOut>
__global__ __launch_bounds__(256) void mfma_gemm(
    const bf16* __restrict__ A, const bf16* __restrict__ Xt,
    const float* __restrict__ bias, const float* __restrict__ res,
    TOut* __restrict__ out, int M, int Nld, int Nw, int Kp, int act,
    int bias_on_n, int bias_len,
    size_t astride, size_t xstride, size_t ostride)
{
    int bt = blockIdx.z;
    A  += (size_t)bt * astride;
    Xt += (size_t)bt * xstride;
    out += (size_t)bt * ostride;
    if (res) res += (size_t)bt * ostride;
    int m0 = blockIdx.y * 128, n0 = blockIdx.x * 128;

    __shared__ uint32_t lds[8192];   // 32 KB

    int tid = threadIdx.x;
    int w = tid >> 6, lane = tid & 63;
    int wr = w >> 1, wc = w & 1;
    int r15 = lane & 15, g = lane >> 4;

    f32x4 zero4 = {0.f, 0.f, 0.f, 0.f};
    f32x4 acc[4][4];
    #pragma unroll
    for (int i = 0; i < 4; i++)
        #pragma unroll
        for (int j = 0; j < 4; j++) acc[i][j] = zero4;

    int nkt = Kp >> 6;
    for (int kt = 0; kt < nkt; kt++) {
        // ---- stage A and B tiles (linear LDS dest, inverse-swizzled source)
        #pragma unroll
        for (int i = 0; i < 4; i++) {
            int row = (w * 4 + i) * 8 + (lane >> 3);   // 0..127
            int us  = (lane & 7) ^ (row & 7);          // source 16B-unit in row
            const bf16* sa = A  + (size_t)(m0 + row) * Kp + kt * 64 + us * 8;
            const bf16* sb = Xt + (size_t)(n0 + row) * Kp + kt * 64 + us * 8;
            stage16(sa, &lds[(w * 4 + i) * 256], lane);
            stage16(sb, &lds[4096 + (w * 4 + i) * 256], lane);
        }
        __syncthreads();

        // ---- fragment reads (swizzled)
        s16x8 af[4][2], bfr[4][2];
        #pragma unroll
        for (int mm = 0; mm < 4; mm++) {
            int r = wr * 64 + mm * 16 + r15;
            #pragma unroll
            for (int ks = 0; ks < 2; ks++) {
                int u = (ks * 4 + g) ^ (r & 7);
                af[mm][ks] = *(const s16x8*)&lds[(unsigned)(r * 8 + u) * 4];
            }
        }
        #pragma unroll
        for (int nn = 0; nn < 4; nn++) {
            int r = wc * 64 + nn * 16 + r15;
            #pragma unroll
            for (int ks = 0; ks < 2; ks++) {
                int u = (ks * 4 + g) ^ (r & 7);
                bfr[nn][ks] = *(const s16x8*)&lds[4096 + (unsigned)(r * 8 + u) * 4];
            }
        }

        #pragma unroll
        for (int ks = 0; ks < 2; ks++)
            #pragma unroll
            for (int mm = 0; mm < 4; mm++)
                #pragma unroll
                for (int nn = 0; nn < 4; nn++)
                    acc[mm][nn] = __builtin_amdgcn_mfma_f32_16x16x32_bf16(
                        af[mm][ks], bfr[nn][ks], acc[mm][nn], 0, 0, 0);
        __syncthreads();
    }

    // ---- epilogue
    #pragma unroll
    for (int mm = 0; mm < 4; mm++) {
        int mbase = m0 + wr * 64 + mm * 16 + g * 4;
        #pragma unroll
        for (int rr = 0; rr < 4; rr++) {
            int m = mbase + rr;
            if (m >= M) continue;
            float bvm = (bias && !bias_on_n) ? bias[m] : 0.f;
            #pragma unroll
            for (int nn = 0; nn < 4; nn++) {
                int n = n0 + wc * 64 + nn * 16 + r15;
                if (n >= Nw) continue;
                float bv = bias_on_n ? ((bias && n < bias_len) ? bias[n] : 0.f) : bvm;
                float v = acc[mm][nn][rr] + bv;
                if (act == 1) v = gelu_tanh(v);
                if (res) v += res[(size_t)m * Nld + n];
                stf(&out[(size_t)m * Nld + n], v);
            }
        }
    }
}

// ---------------------------------------------------------------------------
// Transpose-convert: out[n][r] = bf16(in[r][n]) for r<R else 0.  out: [Ncols][Rpad]
// ---------------------------------------------------------------------------
template <typename TIn>
__global__ __launch_bounds__(256) void transpose_kernel(
    const TIn* __restrict__ in, bf16* __restrict__ out,
    int R, int Ncols, int Rpad, size_t in_z, size_t out_z)
{
    in  += (size_t)blockIdx.z * in_z;
    out += (size_t)blockIdx.z * out_z;
    __shared__ float t[32][33];
    int r0 = blockIdx.y * 32, n0 = blockIdx.x * 32;
    int tx = threadIdx.x & 31, ty = threadIdx.x >> 5;
    #pragma unroll
    for (int s = 0; s < 4; s++) {
        int r = r0 + ty + 8 * s;
        t[ty + 8 * s][tx] = (r < R) ? ldf(&in[(size_t)r * Ncols + n0 + tx]) : 0.f;
    }
    __syncthreads();
    #pragma unroll
    for (int s = 0; s < 4; s++) {
        int n = n0 + ty + 8 * s;
        out[(size_t)n * Rpad + r0 + tx] = __float2bfloat16(t[tx][ty + 8 * s]);
    }
}

// ---------------------------------------------------------------------------
// fp32 [R][Cin] -> bf16 [Rpad][Cout], zero-padded
// ---------------------------------------------------------------------------
__global__ __launch_bounds__(256) void convert_pad_kernel(
    const float* __restrict__ in, bf16* __restrict__ out,
    int R, int Cin, int Cout)
{
    int c = blockIdx.x * 256 + threadIdx.x;
    int r = blockIdx.y;
    if (c >= Cout) return;
    float v = (r < R && c < Cin) ? in[(size_t)r * Cin + c] : 0.f;
    out[(size_t)r * Cout + c] = __float2bfloat16(v);
}

// ---------------------------------------------------------------------------
// Depthwise 3x3, stride 1, pad 1.  One block per 64x64 plane (8 KB), LDS-staged.
// in/out: [B*TC, 64, 64] bf16, wdw: [TC,9] fp32.  256 thr, 16 px/thread.
// ---------------------------------------------------------------------------
__global__ __launch_bounds__(256) void dwconv_kernel(
    const bf16* __restrict__ in, const float* __restrict__ wdw,
    bf16* __restrict__ out)
{
    int plane = blockIdx.x;              // b*TC + c
    int c = plane % TC_;
    const bf16* ip = in + ((size_t)plane << 12);
    bf16*       op = out + ((size_t)plane << 12);

    __shared__ bf16 sp[64][72];          // 144 B rows: balanced banks

    int t = threadIdx.x;
    #pragma unroll
    for (int i = 0; i < 2; i++) {
        int px = (t + 256 * i) * 8;
        int r = px >> 6, col = px & 63;
        *(uint4*)&sp[r][col] = *(const uint4*)&ip[px];
    }
    float w[9];
    #pragma unroll
    for (int k = 0; k < 9; k++) w[k] = wdw[c * 9 + k];
    __syncthreads();

    int row = t >> 2, c0 = (t & 3) * 16;
    float acc[16];
    #pragma unroll
    for (int j = 0; j < 16; j++) acc[j] = 0.f;

    #pragma unroll
    for (int dy = -1; dy <= 1; dy++) {
        int yy = row + dy;
        if (yy < 0 || yy > 63) continue;
        float vals[18];
        vals[0]  = (c0 > 0)       ? __bfloat162float(sp[yy][c0 - 1])  : 0.f;
        s16x8 v0 = *(const s16x8*)&sp[yy][c0];
        s16x8 v1 = *(const s16x8*)&sp[yy][c0 + 8];
        #pragma unroll
        for (int j = 0; j < 8; j++) {
            vals[j + 1] = bfu2f((unsigned short)v0[j]);
            vals[j + 9] = bfu2f((unsigned short)v1[j]);
        }
        vals[17] = (c0 + 16 < 64) ? __bfloat162float(sp[yy][c0 + 16]) : 0.f;
        float w0 = w[(dy + 1) * 3], w1 = w[(dy + 1) * 3 + 1], w2 = w[(dy + 1) * 3 + 2];
        #pragma unroll
        for (int j = 0; j < 16; j++)
            acc[j] += w0 * vals[j] + w1 * vals[j + 1] + w2 * vals[j + 2];
    }

    bf16 ob[16];
    #pragma unroll
    for (int j = 0; j < 16; j++) ob[j] = __float2bfloat16(acc[j]);
    #pragma unroll
    for (int i = 0; i < 2; i++)
        *(uint4*)&op[row * 64 + c0 + i * 8] = *(uint4*)&ob[i * 8];
}

__global__ void zero_kernel(float* __restrict__ p, int n)
{
    int i = blockIdx.x * 256 + threadIdx.x;
    if (i < n) p[i] = 0.f;
}

// ---------------------------------------------------------------------------
// Stage A: partial QK^T + partial squared norms per (b,h), chunked over pixels.
// grid: (chunks=8, bh=64), 256 threads.
// ---------------------------------------------------------------------------
__global__ __launch_bounds__(256) void qk_partial_kernel(
    const bf16* __restrict__ qkv, float* __restrict__ S,
    float* __restrict__ n2q, float* __restrict__ n2k)
{
    int bh = blockIdx.y;
    int b = bh >> 3, h = bh & 7;
    int base = blockIdx.x * 512;
    const bf16* qp = qkv + ((size_t)b * TC_ + h * CH_) * HW_;
    const bf16* kp = qp + (size_t)C_ * HW_;

    __shared__ float qs[32][65], ks[32][65];

    int tid = threadIdx.x;
    int nr = tid >> 3, seg = (tid & 7) * 8;
    float accA[4] = {0.f, 0.f, 0.f, 0.f};
    float sq = 0.f, sk = 0.f;

    for (int t0 = 0; t0 < 512; t0 += 64) {
        #pragma unroll
        for (int i = 0; i < 8; i++) {
            int l = tid + 256 * i;
            int r = l >> 6, cc = l & 63;
            qs[r][cc] = __bfloat162float(qp[(size_t)r * HW_ + base + t0 + cc]);
            ks[r][cc] = __bfloat162float(kp[(size_t)r * HW_ + base + t0 + cc]);
        }
        __syncthreads();
        #pragma unroll
        for (int p = 0; p < 4; p++) {
            int e = tid + 256 * p;
            int i = e >> 5, j = e & 31;
            float s = 0.f;
            #pragma unroll
            for (int kk = 0; kk < 64; kk++) s += qs[i][kk] * ks[j][kk];
            accA[p] += s;
        }
        #pragma unroll
        for (int s = 0; s < 8; s++) {
            float vq = qs[nr][seg + s]; sq += vq * vq;
            float vk = ks[nr][seg + s]; sk += vk * vk;
        }
        __syncthreads();
    }

    #pragma unroll
    for (int off = 1; off < 8; off <<= 1) {
        sq += __shfl_xor(sq, off);
        sk += __shfl_xor(sk, off);
    }
    if ((tid & 7) == 0) {
        atomicAdd(&n2q[bh * 32 + nr], sq);
        atomicAdd(&n2k[bh * 32 + nr], sk);
    }
    #pragma unroll
    for (int p = 0; p < 4; p++) {
        int e = tid + 256 * p;
        atomicAdd(&S[(size_t)bh * 1024 + e], accA[p]);
    }
}

// ---------------------------------------------------------------------------
// Stage B: normalize + softmax.  grid: 64 blocks (bh), 64 threads.
// ---------------------------------------------------------------------------
__global__ __launch_bounds__(64) void softmax_kernel(
    const float* __restrict__ S, const float* __restrict__ n2q,
    const float* __restrict__ n2k, const float* __restrict__ temp,
    float* __restrict__ attnb)
{
    int bh = blockIdx.x, h = bh & 7;
    __shared__ float nkl[32];
    int tid = threadIdx.x;
    if (tid < 32) nkl[tid] = fmaxf(sqrtf(n2k[bh * 32 + tid]), 1e-12f);
    __syncthreads();
    if (tid < 32) {
        float nq = fmaxf(sqrtf(n2q[bh * 32 + tid]), 1e-12f);
        float tp = temp[h];
        float row[32];
        float m = -1e30f;
        #pragma unroll
        for (int j = 0; j < 32; j++) {
            row[j] = S[(size_t)bh * 1024 + tid * 32 + j] * tp / (nq * nkl[j]);
            m = fmaxf(m, row[j]);
        }
        float s = 0.f;
        #pragma unroll
        for (int j = 0; j < 32; j++) { row[j] = expf(row[j] - m); s += row[j]; }
        float inv = 1.f / s;
        #pragma unroll
        for (int j = 0; j < 32; j++)
            attnb[(size_t)bh * 1024 + tid * 32 + j] = row[j] * inv;
    }
}

// ---------------------------------------------------------------------------
// Stage C: Wcomb[b][m][h*32+j] = sum_i w_proj[m][h*32+i] * attn[b][h][i][j]
// out bf16.  grid: 64 blocks (bh), 256 threads (m).
// ---------------------------------------------------------------------------
__global__ __launch_bounds__(256) void wcomb_kernel(
    const float* __restrict__ w_proj, const float* __restrict__ attnb,
    bf16* __restrict__ wcomb)
{
    int bh = blockIdx.x;
    int b = bh >> 3, h = bh & 7;
    __shared__ float at[32][33];
    int tid = threadIdx.x;
    #pragma unroll
    for (int p = 0; p < 4; p++) {
        int e = tid + 256 * p;
        at[e >> 5][e & 31] = attnb[(size_t)bh * 1024 + e];
    }
    __syncthreads();
    int m = tid;
    float wrow[32];
    #pragma unroll
    for (int i = 0; i < 32; i++) wrow[i] = w_proj[(size_t)m * C_ + h * 32 + i];
    #pragma unroll
    for (int j = 0; j < 32; j++) {
        float s = 0.f;
        #pragma unroll
        for (int i = 0; i < 32; i++) s += wrow[i] * at[i][j];
        wcomb[((size_t)b * C_ + m) * C_ + h * 32 + j] = __float2bfloat16(s);
    }
}

// ---------------------------------------------------------------------------
extern "C" void kernel_launch(void* const* d_in, const int* in_sizes, int n_in,
                              void* d_out, int out_size, void* d_ws, size_t ws_size,
                              hipStream_t stream)
{
    const float* x      = (const float*)d_in[0];
    const float* w_qkv  = (const float*)d_in[1];
    const float* w_dw   = (const float*)d_in[2];
    const float* temp   = (const float*)d_in[3];
    const float* w_proj = (const float*)d_in[4];
    const float* w_mlp1 = (const float*)d_in[5];
    const float* b_mlp1 = (const float*)d_in[6];
    const float* w_mlp2 = (const float*)d_in[7];
    const float* b_mlp2 = (const float*)d_in[8];

    char* ws = (char*)d_ws;
    // Lifetimes:
    //  qkv_pre bf16 @0              (50,331,648)  dead after dwconv
    //  xt      bf16 @50,331,648     (16,777,216)  dead after GEMM1  } inside future qkv
    //  wqkv_bf bf16 @67,108,864     (   393,216)  dead after GEMM1  }
    //  qkv     bf16 @50,331,648     (50,331,648)  written by dwconv; dead after GEMM6
    //  x2      f32  @0              (33,554,432)
    //  S_f/n2q/n2k/attnb f32 @33,554,432
    //  wcomb   bf16 @34,095,104     ( 1,048,576)
    //  wm1_bf  bf16 @35,143,680     (   294,912)  [384 x 256 x 2B]
    //  wm2_bf  bf16 @35,438,592     (   163,840)
    //  vt      bf16 @35,602,432     (16,777,216)  (overlaps qkv b0 q-rows; written
    //                                              after qk_partial -> safe)
    //  x2t     bf16 @52,379,648     (16,777,216)  (overlaps dead qkv)
    //  yt      bf16 @72,400,896     (20,971,520)  (overlaps dead qkv)
    bf16*  qkv_pre = (bf16*)ws;
    bf16*  xt      = (bf16*)(ws + (size_t)50331648);
    bf16*  wqkv_bf = (bf16*)(ws + (size_t)67108864);
    bf16*  qkv     = (bf16*)(ws + (size_t)50331648);
    float* x2      = (float*)ws;
    float* S_f     = (float*)(ws + (size_t)33554432);
    float* n2q     = S_f + 65536;
    float* n2k     = n2q + 2048;
    float* attnb   = n2k + 2048;
    bf16*  wcomb   = (bf16*)(ws + (size_t)34095104);
    bf16*  wm1_bf  = (bf16*)(ws + (size_t)35143680);
    bf16*  wm2_bf  = (bf16*)(ws + (size_t)35438592);
    bf16*  vt      = (bf16*)(ws + (size_t)35602432);
    bf16*  x2t     = (bf16*)(ws + (size_t)52379648);
    bf16*  yt      = (bf16*)(ws + (size_t)72400896);

    // 1) weights/inputs to bf16
    convert_pad_kernel<<<dim3(1, TC_), 256, 0, stream>>>(w_qkv, wqkv_bf, TC_, C_, C_);
    transpose_kernel<float><<<dim3(128, 8, B_), 256, 0, stream>>>(
        x, xt, C_, HW_, C_, (size_t)C_ * HW_, (size_t)HW_ * C_);

    // 2) qkv_pre = w_qkv @ x   (M=768, N=4096, K=256)
    mfma_gemm<bf16><<<dim3(32, 6, B_), 256, 0, stream>>>(
        wqkv_bf, xt, nullptr, nullptr, qkv_pre, TC_, HW_, HW_, C_, 0, 0, 0,
        0, (size_t)HW_ * C_, (size_t)TC_ * HW_);

    // 3) qkv = dwconv3x3(qkv_pre)
    dwconv_kernel<<<B_ * TC_, 256, 0, stream>>>(qkv_pre, w_dw, qkv);

    // 4) attention statistics
    zero_kernel<<<(69632 + 255) / 256, 256, 0, stream>>>(S_f, 69632);
    qk_partial_kernel<<<dim3(8, 64), 256, 0, stream>>>(qkv, S_f, n2q, n2k);
    softmax_kernel<<<64, 64, 0, stream>>>(S_f, n2q, n2k, temp, attnb);
    wcomb_kernel<<<64, 256, 0, stream>>>(w_proj, attnb, wcomb);

    // 5) remaining weight converts + v transpose
    convert_pad_kernel<<<dim3(1, HIDM_), 256, 0, stream>>>(w_mlp1, wm1_bf, HID_, C_, C_);
    convert_pad_kernel<<<dim3(2, C_), 256, 0, stream>>>(w_mlp2, wm2_bf, C_, HID_, HIDP_);
    transpose_kernel<bf16><<<dim3(128, 8, B_), 256, 0, stream>>>(
        qkv + (size_t)2 * C_ * HW_, vt, C_, HW_, C_,
        (size_t)TC_ * HW_, (size_t)HW_ * C_);

    // 6) x2 = x + Wcomb[b] @ v   (M=256, N=4096, K=256)
    mfma_gemm<float><<<dim3(32, 2, B_), 256, 0, stream>>>(
        wcomb, vt, nullptr, x, x2, C_, HW_, HW_, C_, 0, 0, 0,
        (size_t)C_ * C_, (size_t)HW_ * C_, (size_t)C_ * HW_);

    // 7) x2t
    transpose_kernel<float><<<dim3(128, 8, B_), 256, 0, stream>>>(
        x2, x2t, C_, HW_, C_, (size_t)C_ * HW_, (size_t)HW_ * C_);

    // 8) yt = gelu(x2t @ w_mlp1^T + b1)^T-free: out[pix][hid], M=4096, N=320
    mfma_gemm<bf16><<<dim3(3, 32, B_), 256, 0, stream>>>(
        x2t, wm1_bf, b_mlp1, nullptr, yt, HW_, HIDP_, HIDP_, C_, 1, 1, HID_,
        (size_t)HW_ * C_, 0, (size_t)HW_ * HIDP_);

    // 9) out = x2 + w_mlp2 @ y + b2   (M=256, N=4096, K=320 padded)
    mfma_gemm<float><<<dim3(32, 2, B_), 256, 0, stream>>>(
        wm2_bf, yt, b_mlp2, x2, (float*)d_out, C_, HW_, HW_, HIDP_, 0, 0, 0,
        0, (size_t)HW_ * HIDP_, (size_t)C_ * HW_);
}